// Round 4
// baseline (183.945 us; speedup 1.0000x reference)
//
#include <hip/hip_runtime.h>
#include <stdint.h>

// ScaledDotProductAttention: B=16, Nq=Nk=4096, d=128, fp32 in/out, causal.
// Flash-attention forward, bf16 MFMA (16x16x32), swapped-QK^T layout so the
// online softmax is lane-local. ws layout: Kb bf16 [B][N][D] (16MB) then
// Vt bf16 [B][D][N] (16MB) -> needs 32MB of d_ws.

#define NB 16
#define NS 4096
#define DH 128

typedef float          fx4  __attribute__((ext_vector_type(4)));
typedef uint32_t       ux4  __attribute__((ext_vector_type(4)));
typedef __bf16         bfv8 __attribute__((ext_vector_type(8)));
typedef unsigned short u16x8 __attribute__((ext_vector_type(8)));
typedef unsigned short u16x4 __attribute__((ext_vector_type(4)));

// fp32 -> bf16 bits, round-to-nearest-even (inputs finite; no NaN handling)
__device__ __forceinline__ unsigned short f2bfu(float x) {
  uint32_t u = __float_as_uint(x);
  u += 0x7fffu + ((u >> 16) & 1u);
  return (unsigned short)(u >> 16);
}

__device__ __forceinline__ fx4 mfma16(bfv8 a, bfv8 b, fx4 c) {
  return __builtin_amdgcn_mfma_f32_16x16x32_bf16(a, b, c, 0, 0, 0);
}

// ---------------- pre-pass 1: K fp32 -> bf16 ----------------
__global__ void __launch_bounds__(256) convert_k_kernel(
    const float* __restrict__ K, unsigned short* __restrict__ Kb) {
  const size_t i = ((size_t)blockIdx.x * 256 + threadIdx.x) * 8;  // exact cover
  fx4 a = *(const fx4*)(K + i);
  fx4 b = *(const fx4*)(K + i + 4);
  unsigned short tmp[8];
#pragma unroll
  for (int j = 0; j < 4; ++j) { tmp[j] = f2bfu(a[j]); tmp[4 + j] = f2bfu(b[j]); }
  *(ux4*)(Kb + i) = *(const ux4*)tmp;
}

// ---------------- pre-pass 2: V fp32 [b][n][d] -> bf16 Vt [b][d][n] ----------------
__global__ void __launch_bounds__(256) transpose_v_kernel(
    const float* __restrict__ V, unsigned short* __restrict__ Vt) {
  __shared__ __align__(16) unsigned short tile[64][72];  // +8 pad
  const int bid = blockIdx.x;
  const int b   = bid >> 7;        // 128 tiles per batch
  const int rem = bid & 127;
  const int tn  = rem >> 1;        // 64 n-tiles
  const int td  = rem & 1;         // 2 d-tiles
  const int n0  = tn << 6, d0 = td << 6;
  const int t   = threadIdx.x;
  {
    const int r = t >> 2, cg = t & 3;
    const float* src = V + (((size_t)(b * NS + n0 + r)) << 7) + d0 + 16 * cg;
    fx4 f0 = *(const fx4*)(src);
    fx4 f1 = *(const fx4*)(src + 4);
    fx4 f2 = *(const fx4*)(src + 8);
    fx4 f3 = *(const fx4*)(src + 12);
    unsigned short tmp[16];
#pragma unroll
    for (int j = 0; j < 4; ++j) {
      tmp[j] = f2bfu(f0[j]); tmp[4 + j] = f2bfu(f1[j]);
      tmp[8 + j] = f2bfu(f2[j]); tmp[12 + j] = f2bfu(f3[j]);
    }
    *(ux4*)&tile[r][16 * cg]     = *(const ux4*)tmp;
    *(ux4*)&tile[r][16 * cg + 8] = *(const ux4*)(tmp + 8);
  }
  __syncthreads();
  {
    const int dd = t >> 2, ng = t & 3;
    unsigned short ov[16];
#pragma unroll
    for (int k = 0; k < 16; ++k) ov[k] = tile[16 * ng + k][dd];
    unsigned short* dst = Vt + (((size_t)(b * DH + d0 + dd)) << 12) + n0 + 16 * ng;
    *(ux4*)dst       = *(const ux4*)ov;
    *(ux4*)(dst + 8) = *(const ux4*)(ov + 8);
  }
}

// ---------------- main: causal flash attention ----------------
// Block: 256 threads = 4 waves; wave w owns q rows [qb+32w, qb+32w+32).
// Per kv-block (64 keys): stage K (64x128 bf16) + Vt (128x64 bf16) in LDS
// (XOR-swizzled, rule #21 both-sides), then per wave:
//   S^T = mfma(Kfrag, Qfrag)   -> lane: q = lane&15, kv = 16*tt + 4*(lane>>4)+r
//   online softmax (lane-local m/l, exp2 domain, defer-max THR=8)
//   O^T += mfma(Vtfrag, Pfrag) -> lane: q = lane&15, d = 16*dt + 4*(lane>>4)+r
__global__ void __launch_bounds__(256, 2) attn_kernel(
    const float* __restrict__ Q, const unsigned short* __restrict__ Kb,
    const unsigned short* __restrict__ Vt, float* __restrict__ O) {
  __shared__ __align__(16) unsigned char sm[32768];  // K: [0,16K), V: [16K,32K)

  const int bid  = blockIdx.x;
  const int b    = bid & 15;
  const int blkq = 31 - (bid >> 4);   // largest-work blocks first
  const int qb   = blkq << 7;
  const int tid  = threadIdx.x;
  const int w    = tid >> 6;
  const int lane = tid & 63;
  const int g    = lane >> 4;
  const int ln16 = lane & 15;
  const int qw   = qb + 32 * w;

  const float SCALE = 0.12753102f;  // log2(e)/sqrt(128): exp2-domain scores

  // Q fragments, pre-scaled, kept in registers for the whole kernel.
  bfv8 qf[2][4];
#pragma unroll
  for (int qt = 0; qt < 2; ++qt) {
#pragma unroll
    for (int c = 0; c < 4; ++c) {
      const float* qp = Q + (((size_t)(b * NS + qw + qt * 16 + ln16)) << 7) + 32 * c + 8 * g;
      fx4 a0 = *(const fx4*)qp;
      fx4 a1 = *(const fx4*)(qp + 4);
      u16x8 t;
#pragma unroll
      for (int j = 0; j < 4; ++j) {
        t[j]     = f2bfu(a0[j] * SCALE);
        t[j + 4] = f2bfu(a1[j] * SCALE);
      }
      qf[qt][c] = __builtin_bit_cast(bfv8, t);
    }
  }

  const fx4 z4 = {0.f, 0.f, 0.f, 0.f};
  fx4 acc[2][8];
#pragma unroll
  for (int qt = 0; qt < 2; ++qt)
#pragma unroll
    for (int dt = 0; dt < 8; ++dt) acc[qt][dt] = z4;
  float mrun[2] = {-1e30f, -1e30f};
  float lsum[2] = {0.f, 0.f};

  const int nkv  = 2 * blkq + 2;            // kv blocks staged by the block
  const int nkvw = ((qw + 31) >> 6) + 1;    // kv blocks this wave computes
  const int swzv = (ln16 & 7) << 4;         // V-read swizzle (row&7 == ln16&7)

  for (int jb = 0; jb < nkv; ++jb) {
    const int kvb = jb << 6;

    // ---- cooperative stage: global(bf16) -> regs -> swizzled LDS ----
    ux4 kr[4], vr[4];
#pragma unroll
    for (int i = 0; i < 4; ++i) {
      int o = i * 4096 + tid * 16;
      int row = o >> 8, cb = o & 255;
      kr[i] = *(const ux4*)(Kb + (((size_t)(b * NS + kvb + row)) << 7) + (cb >> 1));
    }
#pragma unroll
    for (int i = 0; i < 4; ++i) {
      int o = i * 4096 + tid * 16;
      int row = o >> 7, cb = o & 127;
      vr[i] = *(const ux4*)(Vt + (((size_t)(b * DH + row)) << 12) + kvb + (cb >> 1));
    }
#pragma unroll
    for (int i = 0; i < 4; ++i) {
      int o = i * 4096 + tid * 16;
      int row = o >> 8, cb = o & 255;
      *(ux4*)(sm + row * 256 + (cb ^ ((row & 7) << 4))) = kr[i];
    }
#pragma unroll
    for (int i = 0; i < 4; ++i) {
      int o = i * 4096 + tid * 16;
      int row = o >> 7, cb = o & 127;
      *(ux4*)(sm + 16384 + row * 128 + (cb ^ ((row & 7) << 4))) = vr[i];
    }
    __syncthreads();

    if (jb < nkvw) {
      // ---- QK^T (swapped: A=K rows->kv, B=Q cols->q) ----
      fx4 s[2][4];
#pragma unroll
      for (int tt = 0; tt < 4; ++tt) { s[0][tt] = z4; s[1][tt] = z4; }
#pragma unroll
      for (int tt = 0; tt < 4; ++tt) {
        const int row = 16 * tt + ln16;
        const unsigned char* kbase = sm + row * 256;
        const int swz = (row & 7) << 4;
#pragma unroll
        for (int c = 0; c < 4; ++c) {
          bfv8 kf = *(const bfv8*)(kbase + ((64 * c + 16 * g) ^ swz));
          s[0][tt] = mfma16(kf, qf[0][c], s[0][tt]);
          s[1][tt] = mfma16(kf, qf[1][c], s[1][tt]);
        }
      }

      // ---- causal mask (only near-diagonal blocks) ----
      if (kvb + 63 > qw) {
#pragma unroll
        for (int qt = 0; qt < 2; ++qt) {
          const int qrow = qw + qt * 16 + ln16;
#pragma unroll
          for (int tt = 0; tt < 4; ++tt)
#pragma unroll
            for (int r = 0; r < 4; ++r) {
              int kvpos = kvb + 16 * tt + 4 * g + r;
              if (kvpos > qrow) s[qt][tt][r] = -1e30f;
            }
        }
      }

      // ---- online softmax (exp2 domain, lane-local state, defer-max) ----
      bfv8 pb[2][2];
#pragma unroll
      for (int qt = 0; qt < 2; ++qt) {
        float pm = -1e30f;
#pragma unroll
        for (int tt = 0; tt < 4; ++tt)
#pragma unroll
          for (int r = 0; r < 4; ++r) pm = fmaxf(pm, s[qt][tt][r]);
        pm = fmaxf(pm, __shfl_xor(pm, 16));
        pm = fmaxf(pm, __shfl_xor(pm, 32));
        float mq = mrun[qt];
        if (__any(pm > mq + 8.0f)) {  // T13 defer-max: P bounded by 2^8
          float mn = fmaxf(mq, pm);
          float f  = exp2f(mq - mn);
          lsum[qt] *= f;
#pragma unroll
          for (int dt = 0; dt < 8; ++dt) acc[qt][dt] *= f;
          mrun[qt] = mn;
          mq = mn;
        }
        float rs = 0.f;
#pragma unroll
        for (int tt = 0; tt < 4; ++tt)
#pragma unroll
          for (int r = 0; r < 4; ++r) {
            float p = exp2f(s[qt][tt][r] - mq);
            s[qt][tt][r] = p;
            rs += p;
          }
        rs += __shfl_xor(rs, 16);
        rs += __shfl_xor(rs, 32);
        lsum[qt] += rs;
        // pack P^T into B-fragments: chunk c kv-map j<4 -> 32c+4g+j (tile 2c),
        // j>=4 -> 32c+16+4g+(j-4) (tile 2c+1). Must match V-frag map below.
#pragma unroll
        for (int c = 0; c < 2; ++c) {
          u16x8 t;
#pragma unroll
          for (int j = 0; j < 4; ++j) {
            t[j]     = f2bfu(s[qt][2 * c][j]);
            t[j + 4] = f2bfu(s[qt][2 * c + 1][j]);
          }
          pb[qt][c] = __builtin_bit_cast(bfv8, t);
        }
      }

      // ---- PV (A = V^T rows->d, B = P^T cols->q); same kv map as pb ----
#pragma unroll
      for (int dt = 0; dt < 8; ++dt) {
        const unsigned char* vb = sm + 16384 + (16 * dt + ln16) * 128;
#pragma unroll
        for (int c = 0; c < 2; ++c) {
          u16x4 va = *(const u16x4*)(vb + ((64 * c + 8 * g) ^ swzv));
          u16x4 vc = *(const u16x4*)(vb + ((64 * c + 32 + 8 * g) ^ swzv));
          u16x8 vcomb = __builtin_shufflevector(va, vc, 0, 1, 2, 3, 4, 5, 6, 7);
          bfv8 vf = __builtin_bit_cast(bfv8, vcomb);
          acc[0][dt] = mfma16(vf, pb[0][c], acc[0][dt]);
          acc[1][dt] = mfma16(vf, pb[1][c], acc[1][dt]);
        }
      }
    }
    __syncthreads();
  }

  // ---- epilogue: O[q][d] = acc/l ; lane writes float4 per (qt,dt) ----
#pragma unroll
  for (int qt = 0; qt < 2; ++qt) {
    float inv = 1.0f / lsum[qt];
    float* ob = O + (((size_t)(b * NS + qw + qt * 16 + ln16)) << 7) + 4 * g;
#pragma unroll
    for (int dt = 0; dt < 8; ++dt) {
      fx4 o4 = acc[qt][dt] * inv;
      *(fx4*)(ob + 16 * dt) = o4;
    }
  }
}

extern "C" void kernel_launch(void* const* d_in, const int* in_sizes, int n_in,
                              void* d_out, int out_size, void* d_ws, size_t ws_size,
                              hipStream_t stream) {
  (void)in_sizes; (void)n_in; (void)out_size; (void)ws_size;
  const float* Q = (const float*)d_in[0];
  const float* K = (const float*)d_in[1];
  const float* V = (const float*)d_in[2];
  float* O = (float*)d_out;

  unsigned short* Kb = (unsigned short*)d_ws;                 // 16 MB
  unsigned short* Vt = Kb + (size_t)NB * NS * DH;             // +16 MB

  convert_k_kernel<<<dim3(4096), dim3(256), 0, stream>>>(K, Kb);
  transpose_v_kernel<<<dim3(2048), dim3(256), 0, stream>>>(V, Vt);
  attn_kernel<<<dim3(512), dim3(256), 0, stream>>>(Q, Kb, Vt, O);
}

// Round 5
// 161.543 us; speedup vs baseline: 1.1387x; 1.1387x over previous
//
#include <hip/hip_runtime.h>
#include <stdint.h>

// ScaledDotProductAttention: B=16, Nq=Nk=4096, d=128, fp32 in/out, causal.
// Flash forward, bf16 MFMA 16x16x32, swapped-QK^T (lane-local softmax).
// Round-4 structure: K/V are pre-packed into exact MFMA fragment order in
// d_ws; the attention kernel reads fragments straight from global (L1/L2-
// resident), uses NO LDS and NO barriers. ws: Kfrag 16MB + Vfrag 16MB.

#define NB 16
#define NS 4096
#define DH 128
#define FRAG_U16 8192  // u16 elems per (batch, kv-block) fragment tile (16KB)

typedef float          fx4  __attribute__((ext_vector_type(4)));
typedef uint32_t       ux4  __attribute__((ext_vector_type(4)));
typedef __bf16         bfv8 __attribute__((ext_vector_type(8)));

__device__ __forceinline__ fx4 mfma16(bfv8 a, bfv8 b, fx4 c) {
  return __builtin_amdgcn_mfma_f32_16x16x32_bf16(a, b, c, 0, 0, 0);
}

// ---------------- fused prepass: K,V fp32 -> fragment-packed bf16 ----------------
// One block per (batch, kv-block-of-64). Fragment layouts (lane = g*16+ln16):
//  Kfrag[b][kvblk][tt(4)][c(4)][lane(64)][8]: K[b][kvb+16tt+ln16][32c+8g+e]
//  Vfrag[b][kvblk][dt(8)][c(2)][lane(64)][8]: V^T row d=16dt+ln16,
//      kv elems: e<4 -> kvb+32c+4g+e ; e>=4 -> kvb+32c+16+4g+(e-4)
__global__ void __launch_bounds__(256) prepack_kernel(
    const float* __restrict__ K, const float* __restrict__ V,
    unsigned short* __restrict__ Kf, unsigned short* __restrict__ Vf) {
  __shared__ __align__(16) unsigned short tile[64][136];  // V kv x d, +8 pad
  const int bid = blockIdx.x;
  const int b = bid >> 6, kvblk = bid & 63;
  const int kvb = kvblk << 6;
  const int tid = threadIdx.x;
  const size_t fbase = ((size_t)(b * 64 + kvblk)) * FRAG_U16;

  // ---- K fragments (coalesced read: one 128B line per row; write: lane*16B) ----
  {
    const int tt = tid >> 6, lane = tid & 63;
    const int ln16 = lane & 15, g = lane >> 4;
    const float* kp = K + (((size_t)(b * NS + kvb + 16 * tt + ln16)) << 7) + 8 * g;
    unsigned short* op = Kf + fbase + tt * 2048 + lane * 8;
#pragma unroll
    for (int c = 0; c < 4; ++c) {
      fx4 a0 = *(const fx4*)(kp + 32 * c);
      fx4 a1 = *(const fx4*)(kp + 32 * c + 4);
      bfv8 t;
#pragma unroll
      for (int j = 0; j < 4; ++j) {
        t[j]     = (__bf16)a0[j];
        t[j + 4] = (__bf16)a1[j];
      }
      *(ux4*)(op + c * 512) = __builtin_bit_cast(ux4, t);
    }
  }

  // ---- V: stage bf16 tile in LDS, then gather-write fragments ----
  {
    const int r = tid >> 2, cq = tid & 3;
    const float* vp = V + (((size_t)(b * NS + kvb + r)) << 7) + 32 * cq;
#pragma unroll
    for (int h = 0; h < 4; ++h) {
      fx4 f0 = *(const fx4*)(vp + 8 * h);
      fx4 f1 = *(const fx4*)(vp + 8 * h + 4);
      bfv8 t;
#pragma unroll
      for (int j = 0; j < 4; ++j) {
        t[j]     = (__bf16)f0[j];
        t[j + 4] = (__bf16)f1[j];
      }
      *(ux4*)&tile[r][32 * cq + 8 * h] = __builtin_bit_cast(ux4, t);
    }
  }
  __syncthreads();
  {
    const int dt = tid >> 5, c = (tid >> 4) & 1, ln16 = tid & 15;
    const int d = 16 * dt + ln16;
    unsigned short* op = Vf + fbase + dt * 1024 + c * 512 + ln16 * 8;
#pragma unroll
    for (int g = 0; g < 4; ++g) {
      unsigned short e[8];
#pragma unroll
      for (int j = 0; j < 4; ++j) {
        e[j]     = tile[32 * c + 4 * g + j][d];
        e[j + 4] = tile[32 * c + 16 + 4 * g + j][d];
      }
      *(ux4*)(op + g * 128) = *(const ux4*)e;  // lane*8 = (g*16+ln16)*8
    }
  }
}

// ---------------- main: causal flash attention, LDS-free, barrier-free ----------------
// Block: 4 waves; wave w owns q rows [qb+32w, qb+32w+32). Fragments come
// straight from Kf/Vf (L1/L2-resident). bid remap pairs heavy+light q-blocks
// on the same CU slot (bids c and c+256 sum to constant work).
__global__ void __launch_bounds__(256, 2) attn_kernel(
    const float* __restrict__ Q, const unsigned short* __restrict__ Kf,
    const unsigned short* __restrict__ Vf, float* __restrict__ O) {
  const int bid  = blockIdx.x;
  const int half = bid >> 8;
  const int i    = bid & 255;
  const int b    = i & 15;                    // XCD = bid%8 = b%8 -> 2 batches/XCD (L2-fit)
  const int qi   = i >> 4;
  const int blkq = half ? qi : 31 - qi;       // pair (31-k, k): constant work per CU slot
  const int qb   = blkq << 7;
  const int tid  = threadIdx.x;
  const int w    = tid >> 6;
  const int lane = tid & 63;
  const int g    = lane >> 4;
  const int ln16 = lane & 15;
  const int qw   = qb + 32 * w;

  const float SCALE = 0.12753102f;  // log2(e)/sqrt(128): exp2-domain scores

  // Q fragments, pre-scaled, in registers for the whole kernel.
  bfv8 qf[2][4];
#pragma unroll
  for (int qt = 0; qt < 2; ++qt) {
#pragma unroll
    for (int c = 0; c < 4; ++c) {
      const float* qp = Q + (((size_t)(b * NS + qw + qt * 16 + ln16)) << 7) + 32 * c + 8 * g;
      fx4 a0 = *(const fx4*)qp;
      fx4 a1 = *(const fx4*)(qp + 4);
      bfv8 t;
#pragma unroll
      for (int j = 0; j < 4; ++j) {
        t[j]     = (__bf16)(a0[j] * SCALE);
        t[j + 4] = (__bf16)(a1[j] * SCALE);
      }
      qf[qt][c] = t;
    }
  }

  const fx4 z4 = {0.f, 0.f, 0.f, 0.f};
  fx4 acc[2][8];
#pragma unroll
  for (int qt = 0; qt < 2; ++qt)
#pragma unroll
    for (int dt = 0; dt < 8; ++dt) acc[qt][dt] = z4;
  float mrun[2] = {-1e30f, -1e30f};
  float lsum[2] = {0.f, 0.f};

  const int nkvw = ((qw + 31) >> 6) + 1;  // kv blocks this wave needs

  const unsigned short* kfb = Kf + ((size_t)b * 64) * FRAG_U16 + lane * 8;
  const unsigned short* vfb = Vf + ((size_t)b * 64) * FRAG_U16 + lane * 8;

  for (int jb = 0; jb < nkvw; ++jb) {
    const unsigned short* kp = kfb + (size_t)jb * FRAG_U16;
    const unsigned short* vp = vfb + (size_t)jb * FRAG_U16;

    // ---- QK^T (swapped: A=K rows->kv, B=Q cols->q) ----
    fx4 s[2][4];
#pragma unroll
    for (int tt = 0; tt < 4; ++tt) { s[0][tt] = z4; s[1][tt] = z4; }
#pragma unroll
    for (int tt = 0; tt < 4; ++tt) {
#pragma unroll
      for (int c = 0; c < 4; ++c) {
        bfv8 kfr = *(const bfv8*)(kp + tt * 2048 + c * 512);
        s[0][tt] = mfma16(kfr, qf[0][c], s[0][tt]);
        s[1][tt] = mfma16(kfr, qf[1][c], s[1][tt]);
      }
    }

    // ---- prefetch V fragments (latency hides under softmax) ----
    bfv8 vfr[8][2];
#pragma unroll
    for (int dt = 0; dt < 8; ++dt)
#pragma unroll
      for (int c = 0; c < 2; ++c)
        vfr[dt][c] = *(const bfv8*)(vp + dt * 1024 + c * 512);

    // ---- causal mask (near-diagonal blocks only) ----
    const int kvb = jb << 6;
    if (kvb + 63 > qw) {
#pragma unroll
      for (int qt = 0; qt < 2; ++qt) {
        const int qrow = qw + qt * 16 + ln16;
#pragma unroll
        for (int tt = 0; tt < 4; ++tt)
#pragma unroll
          for (int r = 0; r < 4; ++r) {
            int kvpos = kvb + 16 * tt + 4 * g + r;
            if (kvpos > qrow) s[qt][tt][r] = -1e30f;
          }
      }
    }

    // ---- online softmax (exp2 domain, lane-local state, defer-max THR=8) ----
    bfv8 pb[2][2];
#pragma unroll
    for (int qt = 0; qt < 2; ++qt) {
      float pm = -1e30f;
#pragma unroll
      for (int tt = 0; tt < 4; ++tt)
#pragma unroll
        for (int r = 0; r < 4; ++r) pm = fmaxf(pm, s[qt][tt][r]);
      pm = fmaxf(pm, __shfl_xor(pm, 16));
      pm = fmaxf(pm, __shfl_xor(pm, 32));
      float mq = mrun[qt];
      if (__any(pm > mq + 8.0f)) {
        float mn = fmaxf(mq, pm);
        float f  = __builtin_amdgcn_exp2f(mq - mn);
        lsum[qt] *= f;
#pragma unroll
        for (int dt = 0; dt < 8; ++dt) acc[qt][dt] *= f;
        mrun[qt] = mn;
        mq = mn;
      }
      float rs = 0.f;
#pragma unroll
      for (int tt = 0; tt < 4; ++tt)
#pragma unroll
        for (int r = 0; r < 4; ++r) {
          float p = __builtin_amdgcn_exp2f(s[qt][tt][r] - mq);
          s[qt][tt][r] = p;
          rs += p;
        }
      rs += __shfl_xor(rs, 16);
      rs += __shfl_xor(rs, 32);
      lsum[qt] += rs;
      // pack P^T: chunk c elem j<4 -> kv 32c+4g+j (tile 2c), j>=4 ->
      // 32c+16+4g+(j-4) (tile 2c+1) — matches Vfrag elem map exactly.
#pragma unroll
      for (int c = 0; c < 2; ++c) {
        bfv8 t;
#pragma unroll
        for (int j = 0; j < 4; ++j) {
          t[j]     = (__bf16)s[qt][2 * c][j];
          t[j + 4] = (__bf16)s[qt][2 * c + 1][j];
        }
        pb[qt][c] = t;
      }
    }

    // ---- PV (A = V^T rows->d, B = P^T cols->q) ----
#pragma unroll
    for (int dt = 0; dt < 8; ++dt) {
#pragma unroll
      for (int c = 0; c < 2; ++c) {
        acc[0][dt] = mfma16(vfr[dt][c], pb[0][c], acc[0][dt]);
        acc[1][dt] = mfma16(vfr[dt][c], pb[1][c], acc[1][dt]);
      }
    }
  }

  // ---- epilogue: O[q][d] = acc/l ----
#pragma unroll
  for (int qt = 0; qt < 2; ++qt) {
    float inv = 1.0f / lsum[qt];
    float* ob = O + (((size_t)(b * NS + qw + qt * 16 + ln16)) << 7) + 4 * g;
#pragma unroll
    for (int dt = 0; dt < 8; ++dt) {
      fx4 o4 = acc[qt][dt] * inv;
      *(fx4*)(ob + 16 * dt) = o4;
    }
  }
}

extern "C" void kernel_launch(void* const* d_in, const int* in_sizes, int n_in,
                              void* d_out, int out_size, void* d_ws, size_t ws_size,
                              hipStream_t stream) {
  (void)in_sizes; (void)n_in; (void)out_size; (void)ws_size;
  const float* Q = (const float*)d_in[0];
  const float* K = (const float*)d_in[1];
  const float* V = (const float*)d_in[2];
  float* O = (float*)d_out;

  unsigned short* Kf = (unsigned short*)d_ws;              // 16 MB
  unsigned short* Vf = Kf + (size_t)NB * NS * DH;          // +16 MB

  prepack_kernel<<<dim3(NB * 64), dim3(256), 0, stream>>>(K, V, Kf, Vf);
  attn_kernel<<<dim3(512), dim3(256), 0, stream>>>(Q, Kf, Vf, O);
}

// Round 6
// 130.185 us; speedup vs baseline: 1.4129x; 1.2409x over previous
//
#include <hip/hip_runtime.h>
#include <stdint.h>

// ScaledDotProductAttention: B=16, Nq=Nk=4096, d=128, fp32 in/out, causal.
// Flash forward, bf16 MFMA 16x16x32, swapped-QK^T (lane-local softmax).
// Round-5: K/V fragment tiles (prepacked in d_ws) are staged into LDS via
// global_load_lds (identity copy, conflict-free ds_read_b128), double-buffered
// with the minimal 2-phase template: STAGE(next); compute(cur); vmcnt(0);
// raw s_barrier. One barrier per kv-block, no __syncthreads drain.
// ws: Kfrag 16MB + Vfrag 16MB.

#define NB 16
#define NS 4096
#define DH 128
#define FRAG_U16 8192  // u16 elems per (batch, kv-block) fragment tile (16KB)

typedef float          fx4  __attribute__((ext_vector_type(4)));
typedef uint32_t       ux4  __attribute__((ext_vector_type(4)));
typedef __bf16         bfv8 __attribute__((ext_vector_type(8)));

typedef const uint32_t __attribute__((address_space(1))) glob_u32;
typedef uint32_t       __attribute__((address_space(3))) lds_u32;

__device__ __forceinline__ fx4 mfma16(bfv8 a, bfv8 b, fx4 c) {
  return __builtin_amdgcn_mfma_f32_16x16x32_bf16(a, b, c, 0, 0, 0);
}

// ---------------- fused prepass: K,V fp32 -> fragment-packed bf16 ----------------
// One block per (batch, kv-block-of-64). Fragment layouts (lane = g*16+ln16):
//  Kfrag[b][kvblk][tt(4)][c(4)][lane(64)][8]: K[b][kvb+16tt+ln16][32c+8g+e]
//  Vfrag[b][kvblk][dt(8)][c(2)][lane(64)][8]: V^T row d=16dt+ln16,
//      kv elems: e<4 -> kvb+32c+4g+e ; e>=4 -> kvb+32c+16+4g+(e-4)
__global__ void __launch_bounds__(256) prepack_kernel(
    const float* __restrict__ K, const float* __restrict__ V,
    unsigned short* __restrict__ Kf, unsigned short* __restrict__ Vf) {
  __shared__ __align__(16) unsigned short tile[64][136];  // V kv x d, +8 pad
  const int bid = blockIdx.x;
  const int b = bid >> 6, kvblk = bid & 63;
  const int kvb = kvblk << 6;
  const int tid = threadIdx.x;
  const size_t fbase = ((size_t)(b * 64 + kvblk)) * FRAG_U16;

  // ---- K fragments ----
  {
    const int tt = tid >> 6, lane = tid & 63;
    const int ln16 = lane & 15, g = lane >> 4;
    const float* kp = K + (((size_t)(b * NS + kvb + 16 * tt + ln16)) << 7) + 8 * g;
    unsigned short* op = Kf + fbase + tt * 2048 + lane * 8;
#pragma unroll
    for (int c = 0; c < 4; ++c) {
      fx4 a0 = *(const fx4*)(kp + 32 * c);
      fx4 a1 = *(const fx4*)(kp + 32 * c + 4);
      bfv8 t;
#pragma unroll
      for (int j = 0; j < 4; ++j) {
        t[j]     = (__bf16)a0[j];
        t[j + 4] = (__bf16)a1[j];
      }
      *(ux4*)(op + c * 512) = __builtin_bit_cast(ux4, t);
    }
  }

  // ---- V: stage bf16 tile in LDS, then gather-write fragments ----
  {
    const int r = tid >> 2, cq = tid & 3;
    const float* vp = V + (((size_t)(b * NS + kvb + r)) << 7) + 32 * cq;
#pragma unroll
    for (int h = 0; h < 4; ++h) {
      fx4 f0 = *(const fx4*)(vp + 8 * h);
      fx4 f1 = *(const fx4*)(vp + 8 * h + 4);
      bfv8 t;
#pragma unroll
      for (int j = 0; j < 4; ++j) {
        t[j]     = (__bf16)f0[j];
        t[j + 4] = (__bf16)f1[j];
      }
      *(ux4*)&tile[r][32 * cq + 8 * h] = __builtin_bit_cast(ux4, t);
    }
  }
  __syncthreads();
  {
    const int dt = tid >> 5, c = (tid >> 4) & 1, ln16 = tid & 15;
    const int d = 16 * dt + ln16;
    unsigned short* op = Vf + fbase + dt * 1024 + c * 512 + ln16 * 8;
#pragma unroll
    for (int g = 0; g < 4; ++g) {
      unsigned short e[8];
#pragma unroll
      for (int j = 0; j < 4; ++j) {
        e[j]     = tile[32 * c + 4 * g + j][d];
        e[j + 4] = tile[32 * c + 16 + 4 * g + j][d];
      }
      *(ux4*)(op + g * 128) = *(const ux4*)e;  // lane*8 = (g*16+ln16)*8
    }
  }
}

// ---------------- main: causal flash attention, LDS double-buffered ----------------
// Block: 4 waves; wave w owns q rows [qb+32w, qb+32w+32). Each kv-iteration
// the block cooperatively stages the NEXT 32KB fragment tile (K 16K + V 16K)
// into LDS via global_load_lds while computing the current one. Identity
// layout: fragment reads are ds_read_b128 at lane*16 (conflict-free).
__global__ void __launch_bounds__(256, 2) attn_kernel(
    const float* __restrict__ Q, const unsigned short* __restrict__ Kf,
    const unsigned short* __restrict__ Vf, float* __restrict__ O) {
  __shared__ __align__(16) unsigned char sm[65536];  // 2 buffers x (K 16K | V 16K)

  const int bid  = blockIdx.x;
  const int half = bid >> 8;
  const int i    = bid & 255;
  const int b    = i & 15;              // XCD = bid%8 = b%8 -> 2 batches/XCD (L2-fit)
  const int qi   = i >> 4;
  const int blkq = half ? qi : 31 - qi; // pair (31-k, k): constant work per CU slot
  const int qb   = blkq << 7;
  const int tid  = threadIdx.x;
  const int w    = tid >> 6;
  const int lane = tid & 63;
  const int g    = lane >> 4;
  const int ln16 = lane & 15;
  const int qw   = qb + 32 * w;

  const float SCALE = 0.12753102f;  // log2(e)/sqrt(128): exp2-domain scores

  // Q fragments, pre-scaled, in registers for the whole kernel.
  bfv8 qf[2][4];
#pragma unroll
  for (int qt = 0; qt < 2; ++qt) {
#pragma unroll
    for (int c = 0; c < 4; ++c) {
      const float* qp = Q + (((size_t)(b * NS + qw + qt * 16 + ln16)) << 7) + 32 * c + 8 * g;
      fx4 a0 = *(const fx4*)qp;
      fx4 a1 = *(const fx4*)(qp + 4);
      bfv8 t;
#pragma unroll
      for (int j = 0; j < 4; ++j) {
        t[j]     = (__bf16)(a0[j] * SCALE);
        t[j + 4] = (__bf16)(a1[j] * SCALE);
      }
      qf[qt][c] = t;
    }
  }

  const fx4 z4 = {0.f, 0.f, 0.f, 0.f};
  fx4 acc[2][8];
#pragma unroll
  for (int qt = 0; qt < 2; ++qt)
#pragma unroll
    for (int dt = 0; dt < 8; ++dt) acc[qt][dt] = z4;
  float mrun[2] = {-1e30f, -1e30f};
  float lsum[2] = {0.f, 0.f};

  const int nkv  = 2 * blkq + 2;           // kv blocks staged by the block
  const int nkvw = ((qw + 31) >> 6) + 1;   // kv blocks this wave computes

  const unsigned short* kfb = Kf + ((size_t)b * 64) * FRAG_U16;
  const unsigned short* vfb = Vf + ((size_t)b * 64) * FRAG_U16;

  // stage tile jb into LDS buffer at byte offset bufo. Wave w moves 1KB
  // chunks {i*4KB + w*1KB}: lds dst is wave-uniform, HW adds lane*16.
#define STAGE(jb, bufo)                                                        \
  do {                                                                         \
    const unsigned char* gk = (const unsigned char*)(kfb + (size_t)(jb)*FRAG_U16); \
    const unsigned char* gv = (const unsigned char*)(vfb + (size_t)(jb)*FRAG_U16); \
    _Pragma("unroll")                                                          \
    for (int ii = 0; ii < 4; ++ii) {                                           \
      const int off = ii * 4096 + w * 1024;                                    \
      __builtin_amdgcn_global_load_lds((glob_u32*)(gk + off + lane * 16),      \
                                       (lds_u32*)(sm + (bufo) + off), 16, 0, 0); \
      __builtin_amdgcn_global_load_lds((glob_u32*)(gv + off + lane * 16),      \
                                       (lds_u32*)(sm + (bufo) + 16384 + off), 16, 0, 0); \
    }                                                                          \
  } while (0)

  // prologue: stage tile 0 into buffer 0
  STAGE(0, 0);
  asm volatile("s_waitcnt vmcnt(0)" ::: "memory");
  __builtin_amdgcn_s_barrier();
  asm volatile("" ::: "memory");

  int cur = 0;
  for (int jb = 0; jb < nkv; ++jb) {
    if (jb + 1 < nkv) STAGE(jb + 1, (cur ^ 1) * 32768);  // issue early; lands under compute

    if (jb < nkvw) {
      const unsigned char* kb = sm + cur * 32768;
      const unsigned char* vb = kb + 16384;

      // ---- QK^T (swapped: A=K rows->kv, B=Q cols->q) ----
      fx4 s[2][4];
#pragma unroll
      for (int tt = 0; tt < 4; ++tt) { s[0][tt] = z4; s[1][tt] = z4; }
      __builtin_amdgcn_s_setprio(1);
#pragma unroll
      for (int tt = 0; tt < 4; ++tt) {
#pragma unroll
        for (int c = 0; c < 4; ++c) {
          bfv8 kfr = *(const bfv8*)(kb + tt * 4096 + c * 1024 + lane * 16);
          s[0][tt] = mfma16(kfr, qf[0][c], s[0][tt]);
          s[1][tt] = mfma16(kfr, qf[1][c], s[1][tt]);
        }
      }
      __builtin_amdgcn_s_setprio(0);

      // ---- prefetch V fragments from LDS (hides under softmax) ----
      bfv8 vfr[8][2];
#pragma unroll
      for (int dt = 0; dt < 8; ++dt)
#pragma unroll
        for (int c = 0; c < 2; ++c)
          vfr[dt][c] = *(const bfv8*)(vb + dt * 2048 + c * 1024 + lane * 16);

      // ---- causal mask (near-diagonal blocks only) ----
      const int kvb = jb << 6;
      if (kvb + 63 > qw) {
#pragma unroll
        for (int qt = 0; qt < 2; ++qt) {
          const int qrow = qw + qt * 16 + ln16;
#pragma unroll
          for (int tt = 0; tt < 4; ++tt)
#pragma unroll
            for (int r = 0; r < 4; ++r) {
              int kvpos = kvb + 16 * tt + 4 * g + r;
              if (kvpos > qrow) s[qt][tt][r] = -1e30f;
            }
        }
      }

      // ---- online softmax (exp2 domain, lane-local state, defer-max THR=8) ----
      bfv8 pb[2][2];
#pragma unroll
      for (int qt = 0; qt < 2; ++qt) {
        fx4 m4 = __builtin_elementwise_max(
            __builtin_elementwise_max(s[qt][0], s[qt][1]),
            __builtin_elementwise_max(s[qt][2], s[qt][3]));
        float pm = fmaxf(fmaxf(m4[0], m4[1]), fmaxf(m4[2], m4[3]));
        pm = fmaxf(pm, __shfl_xor(pm, 16));
        pm = fmaxf(pm, __shfl_xor(pm, 32));
        float mq = mrun[qt];
        if (__any(pm > mq + 8.0f)) {
          float mn = fmaxf(mq, pm);
          float f  = __builtin_amdgcn_exp2f(mq - mn);
          lsum[qt] *= f;
#pragma unroll
          for (int dt = 0; dt < 8; ++dt) acc[qt][dt] *= f;
          mrun[qt] = mn;
          mq = mn;
        }
#pragma unroll
        for (int tt = 0; tt < 4; ++tt)
#pragma unroll
          for (int r = 0; r < 4; ++r)
            s[qt][tt][r] = __builtin_amdgcn_exp2f(s[qt][tt][r] - mq);
        fx4 r4 = (s[qt][0] + s[qt][1]) + (s[qt][2] + s[qt][3]);
        float rs = (r4[0] + r4[1]) + (r4[2] + r4[3]);
        rs += __shfl_xor(rs, 16);
        rs += __shfl_xor(rs, 32);
        lsum[qt] += rs;
        // pack P^T: chunk c elem j<4 -> kv 32c+4g+j (tile 2c), j>=4 ->
        // 32c+16+4g+(j-4) (tile 2c+1) — matches Vfrag elem map exactly.
#pragma unroll
        for (int c = 0; c < 2; ++c) {
          bfv8 t;
#pragma unroll
          for (int j = 0; j < 4; ++j) {
            t[j]     = (__bf16)s[qt][2 * c][j];
            t[j + 4] = (__bf16)s[qt][2 * c + 1][j];
          }
          pb[qt][c] = t;
        }
      }

      // ---- PV (A = V^T rows->d, B = P^T cols->q) ----
      __builtin_amdgcn_s_setprio(1);
#pragma unroll
      for (int dt = 0; dt < 8; ++dt) {
#pragma unroll
        for (int c = 0; c < 2; ++c) {
          acc[0][dt] = mfma16(vfr[dt][c], pb[0][c], acc[0][dt]);
          acc[1][dt] = mfma16(vfr[dt][c], pb[1][c], acc[1][dt]);
        }
      }
      __builtin_amdgcn_s_setprio(0);
    }

    // single per-iteration sync: next-tile loads drained (latency was covered
    // by this iteration's compute), then raw barrier. No lgkmcnt/vmcnt drain
    // beyond what's needed; no __syncthreads full-drain semantics.
    asm volatile("s_waitcnt vmcnt(0)" ::: "memory");
    __builtin_amdgcn_s_barrier();
    asm volatile("" ::: "memory");
    cur ^= 1;
  }
#undef STAGE

  // ---- epilogue: O[q][d] = acc/l ----
#pragma unroll
  for (int qt = 0; qt < 2; ++qt) {
    float inv = 1.0f / lsum[qt];
    float* ob = O + (((size_t)(b * NS + qw + qt * 16 + ln16)) << 7) + 4 * g;
#pragma unroll
    for (int dt = 0; dt < 8; ++dt) {
      fx4 o4 = acc[qt][dt] * inv;
      *(fx4*)(ob + 16 * dt) = o4;
    }
  }
}

extern "C" void kernel_launch(void* const* d_in, const int* in_sizes, int n_in,
                              void* d_out, int out_size, void* d_ws, size_t ws_size,
                              hipStream_t stream) {
  (void)in_sizes; (void)n_in; (void)out_size; (void)ws_size;
  const float* Q = (const float*)d_in[0];
  const float* K = (const float*)d_in[1];
  const float* V = (const float*)d_in[2];
  float* O = (float*)d_out;

  unsigned short* Kf = (unsigned short*)d_ws;              // 16 MB
  unsigned short* Vf = Kf + (size_t)NB * NS * DH;          // +16 MB

  prepack_kernel<<<dim3(NB * 64), dim3(256), 0, stream>>>(K, V, Kf, Vf);
  attn_kernel<<<dim3(512), dim3(256), 0, stream>>>(Q, Kf, Vf, O);
}

// Round 7
// 118.298 us; speedup vs baseline: 1.5549x; 1.1005x over previous
//
#include <hip/hip_runtime.h>
#include <stdint.h>

// ScaledDotProductAttention: B=16, Nq=Nk=4096, d=128, fp32 in/out, causal.
// Flash forward, bf16 MFMA 16x16x32, swapped-QK^T (lane-local softmax).
// Round-6: load-balanced kv-chunking. Heavy q-tiles (t>=16) are split into
// two kv-chunks processed by different blocks (partial m/l/acc + merge pass),
// so all 512 workers run 32-34 kv-iterations => 2 blocks/CU co-resident for
// the whole kernel (8 waves/CU steady) instead of a decaying 4.7.
// ws: Kfrag 16MB | Vfrag 16MB | Pa bf16 8MB | Ml 0.5MB  (fallback if smaller).

#define NB 16
#define NS 4096
#define DH 128
#define FRAG_U16 8192  // u16 elems per (batch, kv-block) fragment tile (16KB)

typedef float          fx4   __attribute__((ext_vector_type(4)));
typedef uint32_t       ux4   __attribute__((ext_vector_type(4)));
typedef __bf16         bfv8  __attribute__((ext_vector_type(8)));
typedef __bf16         bfv4  __attribute__((ext_vector_type(4)));
typedef unsigned short u16x4 __attribute__((ext_vector_type(4)));

typedef const uint32_t __attribute__((address_space(1))) glob_u32;
typedef uint32_t       __attribute__((address_space(3))) lds_u32;

__device__ __forceinline__ fx4 mfma16(bfv8 a, bfv8 b, fx4 c) {
  return __builtin_amdgcn_mfma_f32_16x16x32_bf16(a, b, c, 0, 0, 0);
}

// ---------------- fused prepass: K,V fp32 -> fragment-packed bf16 ----------------
// One block per (batch, kv-block-of-64). Fragment layouts (lane = g*16+ln16):
//  Kfrag[b][kvblk][tt(4)][c(4)][lane(64)][8]: K[b][kvb+16tt+ln16][32c+8g+e]
//  Vfrag[b][kvblk][dt(8)][c(2)][lane(64)][8]: V^T row d=16dt+ln16,
//      kv elems: e<4 -> kvb+32c+4g+e ; e>=4 -> kvb+32c+16+4g+(e-4)
__global__ void __launch_bounds__(256) prepack_kernel(
    const float* __restrict__ K, const float* __restrict__ V,
    unsigned short* __restrict__ Kf, unsigned short* __restrict__ Vf) {
  __shared__ __align__(16) unsigned short tile[64][136];  // V kv x d, +8 pad
  const int bid = blockIdx.x;
  const int b = bid >> 6, kvblk = bid & 63;
  const int kvb = kvblk << 6;
  const int tid = threadIdx.x;
  const size_t fbase = ((size_t)(b * 64 + kvblk)) * FRAG_U16;

  // ---- K fragments ----
  {
    const int tt = tid >> 6, lane = tid & 63;
    const int ln16 = lane & 15, g = lane >> 4;
    const float* kp = K + (((size_t)(b * NS + kvb + 16 * tt + ln16)) << 7) + 8 * g;
    unsigned short* op = Kf + fbase + tt * 2048 + lane * 8;
#pragma unroll
    for (int c = 0; c < 4; ++c) {
      fx4 a0 = *(const fx4*)(kp + 32 * c);
      fx4 a1 = *(const fx4*)(kp + 32 * c + 4);
      bfv8 t;
#pragma unroll
      for (int j = 0; j < 4; ++j) {
        t[j]     = (__bf16)a0[j];
        t[j + 4] = (__bf16)a1[j];
      }
      *(ux4*)(op + c * 512) = __builtin_bit_cast(ux4, t);
    }
  }

  // ---- V: stage bf16 tile in LDS, then gather-write fragments ----
  {
    const int r = tid >> 2, cq = tid & 3;
    const float* vp = V + (((size_t)(b * NS + kvb + r)) << 7) + 32 * cq;
#pragma unroll
    for (int h = 0; h < 4; ++h) {
      fx4 f0 = *(const fx4*)(vp + 8 * h);
      fx4 f1 = *(const fx4*)(vp + 8 * h + 4);
      bfv8 t;
#pragma unroll
      for (int j = 0; j < 4; ++j) {
        t[j]     = (__bf16)f0[j];
        t[j + 4] = (__bf16)f1[j];
      }
      *(ux4*)&tile[r][32 * cq + 8 * h] = __builtin_bit_cast(ux4, t);
    }
  }
  __syncthreads();
  {
    const int dt = tid >> 5, c = (tid >> 4) & 1, ln16 = tid & 15;
    const int d = 16 * dt + ln16;
    unsigned short* op = Vf + fbase + dt * 1024 + c * 512 + ln16 * 8;
#pragma unroll
    for (int g = 0; g < 4; ++g) {
      unsigned short e[8];
#pragma unroll
      for (int j = 0; j < 4; ++j) {
        e[j]     = tile[32 * c + 4 * g + j][d];
        e[j + 4] = tile[32 * c + 16 + 4 * g + j][d];
      }
      *(ux4*)(op + g * 128) = *(const ux4*)e;  // lane*8 = (g*16+ln16)*8
    }
  }
}

// ---------------- main: causal flash attention, chunked + LDS double-buffered ----------------
// Worker wid (512, 2/CU):
//  split: wid<256  -> chunk0 of tile t=16+(wid>>4): kv blocks [0,32), mode 1
//         wid>=256 -> chunk1 of tile 31-p: kv [32, 64-2p), mode 2 (32-2p it)
//                     THEN full tile p: kv [0, 2p+2), mode 0      (sum = 34)
//  mode 0: O = acc/l.  mode 1: raw acc -> O, (m,l) -> Ml slot0.
//  mode 2: acc -> Pa (bf16), (m,l) -> Ml slot1.
__global__ void __launch_bounds__(256, 2) attn_kernel(
    const float* __restrict__ Q, const unsigned short* __restrict__ Kf,
    const unsigned short* __restrict__ Vf, float* __restrict__ O,
    unsigned short* __restrict__ Pa, float* __restrict__ Ml, int split) {
  __shared__ __align__(16) unsigned char sm[65536];  // 2 buffers x (K 16K | V 16K)

  const int wid  = blockIdx.x;
  const int tid  = threadIdx.x;
  const int w    = tid >> 6;
  const int lane = tid & 63;
  const int g    = lane >> 4;
  const int ln16 = lane & 15;

  int b, t, j0, nc, mode, two = 0, t2 = 0;
  if (split) {
    if (wid < 256) {
      b = wid & 15; t = 16 + (wid >> 4); j0 = 0; nc = 32; mode = 1;
    } else {
      const int u = wid - 256, p = u >> 4;
      b = u & 15; t = 31 - p; j0 = 32; nc = 32 - 2 * p; mode = 2;
      two = 1; t2 = p;
    }
  } else {  // fallback: round-5 static pairing, no partials
    const int half = wid >> 8, i = wid & 255;
    b = i & 15;
    const int qi = i >> 4;
    t = half ? qi : 31 - qi; j0 = 0; nc = 2 * t + 2; mode = 0;
  }

  const float SCALE = 0.12753102f;  // log2(e)/sqrt(128): exp2-domain scores
  const fx4 z4 = {0.f, 0.f, 0.f, 0.f};

  const unsigned short* kfb = Kf + ((size_t)b * 64) * FRAG_U16;
  const unsigned short* vfb = Vf + ((size_t)b * 64) * FRAG_U16;

  // stage tile jb into LDS buffer at byte offset bufo. Wave w moves 1KB
  // chunks {ii*4KB + w*1KB}: lds dst is wave-uniform, HW adds lane*16.
#define STAGE(jb, bufo)                                                        \
  do {                                                                         \
    const unsigned char* gk = (const unsigned char*)(kfb + (size_t)(jb)*FRAG_U16); \
    const unsigned char* gv = (const unsigned char*)(vfb + (size_t)(jb)*FRAG_U16); \
    _Pragma("unroll")                                                          \
    for (int ii = 0; ii < 4; ++ii) {                                           \
      const int off = ii * 4096 + w * 1024;                                    \
      __builtin_amdgcn_global_load_lds((glob_u32*)(gk + off + lane * 16),      \
                                       (lds_u32*)(sm + (bufo) + off), 16, 0, 0); \
      __builtin_amdgcn_global_load_lds((glob_u32*)(gv + off + lane * 16),      \
                                       (lds_u32*)(sm + (bufo) + 16384 + off), 16, 0, 0); \
    }                                                                          \
  } while (0)

  for (;;) {  // 1 or 2 work items per worker
    const int qb = t << 7;
    const int qw = qb + 32 * w;

    // Q fragments, pre-scaled, in registers for this item.
    bfv8 qf[2][4];
#pragma unroll
    for (int qt = 0; qt < 2; ++qt) {
#pragma unroll
      for (int c = 0; c < 4; ++c) {
        const float* qp = Q + (((size_t)(b * NS + qw + qt * 16 + ln16)) << 7) + 32 * c + 8 * g;
        fx4 a0 = *(const fx4*)qp;
        fx4 a1 = *(const fx4*)(qp + 4);
        bfv8 tt_;
#pragma unroll
        for (int j = 0; j < 4; ++j) {
          tt_[j]     = (__bf16)(a0[j] * SCALE);
          tt_[j + 4] = (__bf16)(a1[j] * SCALE);
        }
        qf[qt][c] = tt_;
      }
    }

    fx4 acc[2][8];
#pragma unroll
    for (int qt = 0; qt < 2; ++qt)
#pragma unroll
      for (int dt = 0; dt < 8; ++dt) acc[qt][dt] = z4;
    float mrun[2] = {-1e30f, -1e30f};
    float lsum[2] = {0.f, 0.f};

    const int nkvw = ((qw + 31) >> 6) + 1;  // causal limit (absolute kv blocks)
    const int jend = j0 + nc;

    // prologue: stage first tile into buffer 0
    STAGE(j0, 0);
    asm volatile("s_waitcnt vmcnt(0)" ::: "memory");
    __builtin_amdgcn_s_barrier();
    asm volatile("" ::: "memory");

    int cur = 0;
    for (int jb = j0; jb < jend; ++jb) {
      if (jb + 1 < jend) STAGE(jb + 1, (cur ^ 1) * 32768);

      if (jb < nkvw) {
        const unsigned char* kb = sm + cur * 32768;
        const unsigned char* vb = kb + 16384;

        // ---- QK^T (swapped: A=K rows->kv, B=Q cols->q) ----
        fx4 s[2][4];
#pragma unroll
        for (int tt = 0; tt < 4; ++tt) { s[0][tt] = z4; s[1][tt] = z4; }
        __builtin_amdgcn_s_setprio(1);
#pragma unroll
        for (int tt = 0; tt < 4; ++tt) {
#pragma unroll
          for (int c = 0; c < 4; ++c) {
            bfv8 kfr = *(const bfv8*)(kb + tt * 4096 + c * 1024 + lane * 16);
            s[0][tt] = mfma16(kfr, qf[0][c], s[0][tt]);
            s[1][tt] = mfma16(kfr, qf[1][c], s[1][tt]);
          }
        }
        __builtin_amdgcn_s_setprio(0);

        // ---- prefetch V fragments from LDS (hides under softmax) ----
        bfv8 vfr[8][2];
#pragma unroll
        for (int dt = 0; dt < 8; ++dt)
#pragma unroll
          for (int c = 0; c < 2; ++c)
            vfr[dt][c] = *(const bfv8*)(vb + dt * 2048 + c * 1024 + lane * 16);

        // ---- causal mask (near-diagonal blocks only) ----
        const int kvb = jb << 6;
        if (kvb + 63 > qw) {
#pragma unroll
          for (int qt = 0; qt < 2; ++qt) {
            const int qrow = qw + qt * 16 + ln16;
#pragma unroll
            for (int tt = 0; tt < 4; ++tt)
#pragma unroll
              for (int r = 0; r < 4; ++r) {
                int kvpos = kvb + 16 * tt + 4 * g + r;
                if (kvpos > qrow) s[qt][tt][r] = -1e30f;
              }
          }
        }

        // ---- online softmax (exp2 domain, lane-local state, defer-max THR=8) ----
        bfv8 pb[2][2];
#pragma unroll
        for (int qt = 0; qt < 2; ++qt) {
          fx4 m4 = __builtin_elementwise_max(
              __builtin_elementwise_max(s[qt][0], s[qt][1]),
              __builtin_elementwise_max(s[qt][2], s[qt][3]));
          float pm = fmaxf(fmaxf(m4[0], m4[1]), fmaxf(m4[2], m4[3]));
          pm = fmaxf(pm, __shfl_xor(pm, 16));
          pm = fmaxf(pm, __shfl_xor(pm, 32));
          float mq = mrun[qt];
          if (__any(pm > mq + 8.0f)) {
            float mn = fmaxf(mq, pm);
            float f  = __builtin_amdgcn_exp2f(mq - mn);
            lsum[qt] *= f;
#pragma unroll
            for (int dt = 0; dt < 8; ++dt) acc[qt][dt] *= f;
            mrun[qt] = mn;
            mq = mn;
          }
#pragma unroll
          for (int tt = 0; tt < 4; ++tt)
#pragma unroll
            for (int r = 0; r < 4; ++r)
              s[qt][tt][r] = __builtin_amdgcn_exp2f(s[qt][tt][r] - mq);
          fx4 r4 = (s[qt][0] + s[qt][1]) + (s[qt][2] + s[qt][3]);
          float rs = (r4[0] + r4[1]) + (r4[2] + r4[3]);
          rs += __shfl_xor(rs, 16);
          rs += __shfl_xor(rs, 32);
          lsum[qt] += rs;
          // pack P^T: chunk c elem j<4 -> kv 32c+4g+j (tile 2c), j>=4 ->
          // 32c+16+4g+(j-4) (tile 2c+1) — matches Vfrag elem map exactly.
#pragma unroll
          for (int c = 0; c < 2; ++c) {
            bfv8 tt_;
#pragma unroll
            for (int j = 0; j < 4; ++j) {
              tt_[j]     = (__bf16)s[qt][2 * c][j];
              tt_[j + 4] = (__bf16)s[qt][2 * c + 1][j];
            }
            pb[qt][c] = tt_;
          }
        }

        // ---- PV (A = V^T rows->d, B = P^T cols->q) ----
        __builtin_amdgcn_s_setprio(1);
#pragma unroll
        for (int dt = 0; dt < 8; ++dt) {
#pragma unroll
          for (int c = 0; c < 2; ++c) {
            acc[0][dt] = mfma16(vfr[dt][c], pb[0][c], acc[0][dt]);
            acc[1][dt] = mfma16(vfr[dt][c], pb[1][c], acc[1][dt]);
          }
        }
        __builtin_amdgcn_s_setprio(0);
      }

      asm volatile("s_waitcnt vmcnt(0)" ::: "memory");
      __builtin_amdgcn_s_barrier();
      asm volatile("" ::: "memory");
      cur ^= 1;
    }

    // ---- epilogue per mode ----
    if (mode == 0) {  // final: O = acc/l
#pragma unroll
      for (int qt = 0; qt < 2; ++qt) {
        float inv = 1.0f / lsum[qt];
        float* ob = O + (((size_t)(b * NS + qw + qt * 16 + ln16)) << 7) + 4 * g;
#pragma unroll
        for (int dt = 0; dt < 8; ++dt) *(fx4*)(ob + 16 * dt) = acc[qt][dt] * inv;
      }
    } else {
      if (mode == 1) {  // chunk0: raw acc -> O (merged later)
#pragma unroll
        for (int qt = 0; qt < 2; ++qt) {
          float* ob = O + (((size_t)(b * NS + qw + qt * 16 + ln16)) << 7) + 4 * g;
#pragma unroll
          for (int dt = 0; dt < 8; ++dt) *(fx4*)(ob + 16 * dt) = acc[qt][dt];
        }
      } else {  // chunk1: acc -> Pa (bf16)
#pragma unroll
        for (int qt = 0; qt < 2; ++qt) {
          const int row = 32 * w + 16 * qt + ln16;
          unsigned short* pp =
              Pa + (((size_t)((b * 16 + (t - 16)) * 128 + row)) << 7) + 4 * g;
#pragma unroll
          for (int dt = 0; dt < 8; ++dt) {
            bfv4 t4;
#pragma unroll
            for (int j = 0; j < 4; ++j) t4[j] = (__bf16)acc[qt][dt][j];
            *(u16x4*)(pp + 16 * dt) = __builtin_bit_cast(u16x4, t4);
          }
        }
      }
      if (g == 0) {  // (m,l): Ml[b][t-16][slot][2][128]
        const int slot = mode - 1;
        float* mlp = Ml + (size_t)(((b * 16 + (t - 16)) * 2 + slot) * 2) * 128;
#pragma unroll
        for (int qt = 0; qt < 2; ++qt) {
          const int row = 32 * w + 16 * qt + ln16;
          mlp[row]       = mrun[qt];
          mlp[128 + row] = lsum[qt];
        }
      }
    }

    if (!two) break;
    two = 0; t = t2; j0 = 0; nc = 2 * t2 + 2; mode = 0;
  }
#undef STAGE
}

// ---------------- merge: combine chunk0 (raw f32 in O) with chunk1 (bf16 Pa) ----------------
__global__ void __launch_bounds__(256) merge_kernel(
    float* __restrict__ O, const unsigned short* __restrict__ Pa,
    const float* __restrict__ Ml) {
  const int gid = blockIdx.x * 256 + threadIdx.x;  // 1,048,576 threads exact
  const int d4  = gid & 31;
  const int rg  = gid >> 5;       // global split-row id, 0..32767
  const int b   = rg >> 11;
  const int r2  = rg & 2047;
  const int tt  = r2 >> 7;        // tile t = 16+tt
  const int row = r2 & 127;

  const float* mlp = Ml + (size_t)((b * 16 + tt) * 4) * 128;
  const float m1 = mlp[row],       l1 = mlp[128 + row];
  const float m2 = mlp[256 + row], l2 = mlp[384 + row];
  const float m  = fmaxf(m1, m2);
  const float w1 = __builtin_amdgcn_exp2f(m1 - m);
  const float w2 = __builtin_amdgcn_exp2f(m2 - m);

  float* op = O + (((size_t)(b * NS + (16 + tt) * 128 + row)) << 7) + 4 * d4;
  fx4 a1 = *(const fx4*)op;
  const unsigned short* pp =
      Pa + (((size_t)((b * 16 + tt) * 128 + row)) << 7) + 4 * d4;
  bfv4 a2b = __builtin_bit_cast(bfv4, *(const u16x4*)pp);
  fx4 a2;
#pragma unroll
  for (int j = 0; j < 4; ++j) a2[j] = (float)a2b[j];

  const float inv = 1.0f / (w1 * l1 + w2 * l2);
  fx4 o = (a1 * w1 + a2 * w2) * inv;
  *(fx4*)op = o;
}

extern "C" void kernel_launch(void* const* d_in, const int* in_sizes, int n_in,
                              void* d_out, int out_size, void* d_ws, size_t ws_size,
                              hipStream_t stream) {
  (void)in_sizes; (void)n_in; (void)out_size;
  const float* Q = (const float*)d_in[0];
  const float* K = (const float*)d_in[1];
  const float* V = (const float*)d_in[2];
  float* O = (float*)d_out;

  unsigned short* Kf = (unsigned short*)d_ws;               // 16 MB
  unsigned short* Vf = Kf + (size_t)NB * NS * DH;           // +16 MB
  unsigned short* Pa = Vf + (size_t)NB * NS * DH;           // +8 MB  (bf16 partials)
  float*          Ml = (float*)((char*)d_ws + 41943040);    // +512 KB (m,l)

  const size_t NEED = 41943040 + 524288;  // 42,467,328 B
  const int split = (ws_size >= NEED) ? 1 : 0;

  prepack_kernel<<<dim3(NB * 64), dim3(256), 0, stream>>>(K, V, Kf, Vf);
  attn_kernel<<<dim3(512), dim3(256), 0, stream>>>(Q, Kf, Vf, O, Pa, Ml, split);
  if (split) merge_kernel<<<dim3(4096), dim3(256), 0, stream>>>(O, Pa, Ml);
}